// Round 9
// baseline (673.308 us; speedup 1.0000x reference)
//
#include <hip/hip_runtime.h>

// out[n] = sum_{e: dst_e = n} (x2[src_e] - x2[dst_e]),  x2 = x @ W   (bias cancels)
// Pipeline: MFMA bf16 GEMM x@W -> x2f (fp32) + x2b (bf16); CSR build via
// count / scan / BINNED fill (bucket append + per-bucket LDS counting sort);
// gather: one wave per node; src-sum from bf16 x2, self term from fp32 x2.

#define C_DIM 128

typedef __attribute__((ext_vector_type(8))) short bf16x8;
typedef __attribute__((ext_vector_type(4))) float f32x4;

__device__ __forceinline__ ushort f2b(float f) {   // fp32 -> bf16 RNE
    uint u = __float_as_uint(f);
    u = (u + 0x7FFFu + ((u >> 16) & 1u)) >> 16;
    return (ushort)u;
}
__device__ __forceinline__ float b2f_lo(uint u) { return __uint_as_float(u << 16); }
__device__ __forceinline__ float b2f_hi(uint u) { return __uint_as_float(u & 0xFFFF0000u); }

// ---------------- MFMA GEMM (unchanged from r8) ----------------
__global__ __launch_bounds__(256) void gemm_mfma(const float* __restrict__ x,
                                                 const float* __restrict__ W,
                                                 float* __restrict__ x2f,
                                                 ushort* __restrict__ x2b,
                                                 int nrows) {
    __shared__ ushort Wt[128 * 128];   // 32 KB
    const int tid = threadIdx.x;
    for (int i = tid; i < 4096; i += 256) {
        int k = i >> 5, n0 = (i & 31) * 4;
        float4 w = *(const float4*)(W + k * 128 + n0);
        float wv[4] = {w.x, w.y, w.z, w.w};
#pragma unroll
        for (int j = 0; j < 4; j++) {
            int n = n0 + j;
            Wt[(n * 128 + k) ^ ((n & 7) << 3)] = f2b(wv[j]);
        }
    }
    __syncthreads();

    const int wv_ = tid >> 6;
    const int lane = tid & 63;
    const int ln = lane & 15, kg = lane >> 4;
    const int row_base = blockIdx.x * 128 + wv_ * 32;

    f32x4 acc[2][8];
#pragma unroll
    for (int a = 0; a < 2; a++)
#pragma unroll
        for (int b = 0; b < 8; b++) acc[a][b] = (f32x4)(0.f);

#pragma unroll
    for (int step = 0; step < 4; step++) {
        const int k0 = step * 32 + kg * 8;
        bf16x8 bfr[8];
#pragma unroll
        for (int cf = 0; cf < 8; cf++) {
            int n = cf * 16 + ln;
            bfr[cf] = *(const bf16x8*)&Wt[(n * 128 + k0) ^ ((n & 7) << 3)];
        }
#pragma unroll
        for (int mf = 0; mf < 2; mf++) {
            int row = row_base + mf * 16 + ln;
            bf16x8 afr;
#pragma unroll
            for (int j = 0; j < 8; j++) afr[j] = 0;
            if (row < nrows) {
                const float4* ap = (const float4*)(x + (size_t)row * 128 + k0);
                float4 a0 = ap[0], a1 = ap[1];
                float av[8] = {a0.x, a0.y, a0.z, a0.w, a1.x, a1.y, a1.z, a1.w};
#pragma unroll
                for (int j = 0; j < 8; j++) afr[j] = (short)f2b(av[j]);
            }
#pragma unroll
            for (int cf = 0; cf < 8; cf++)
                acc[mf][cf] = __builtin_amdgcn_mfma_f32_16x16x32_bf16(afr, bfr[cf], acc[mf][cf], 0, 0, 0);
        }
    }

#pragma unroll
    for (int mf = 0; mf < 2; mf++) {
#pragma unroll
        for (int j = 0; j < 4; j++) {
            int row = row_base + mf * 16 + kg * 4 + j;
            if (row >= nrows) continue;
#pragma unroll
            for (int cf = 0; cf < 8; cf++) {
                float v = acc[mf][cf][j];
                int col = cf * 16 + ln;
                x2f[(size_t)row * 128 + col] = v;
                if (x2b) x2b[(size_t)row * 128 + col] = f2b(v);
            }
        }
    }
}

// ---------------- CSR build ----------------
__global__ __launch_bounds__(256) void zero_ints(int* p, int n) {
    int i = blockIdx.x * 256 + threadIdx.x;
    if (i < n) p[i] = 0;
}

__global__ __launch_bounds__(256) void count_deg(const int* __restrict__ ei,
                                                 int* __restrict__ cnt, int ne, int nn) {
    int e = blockIdx.x * 256 + threadIdx.x;
    if (e >= ne) return;
    int dst = ei[e];
    if ((unsigned)dst < (unsigned)nn) atomicAdd(&cnt[dst], 1);
}

__global__ __launch_bounds__(256) void scan_partials(const int* __restrict__ cnt,
                                                     int* __restrict__ bsum, int n) {
    __shared__ int red[256];
    int i = blockIdx.x * 1024 + threadIdx.x * 4;
    int s = 0;
    if (i + 3 < n) {
        int4 v = *(const int4*)(cnt + i);
        s = v.x + v.y + v.z + v.w;
    } else {
        for (int j = i; j < n && j < i + 4; j++) s += cnt[j];
    }
    red[threadIdx.x] = s;
    __syncthreads();
    for (int off = 128; off > 0; off >>= 1) {
        if (threadIdx.x < off) red[threadIdx.x] += red[threadIdx.x + off];
        __syncthreads();
    }
    if (threadIdx.x == 0) bsum[blockIdx.x] = red[0];
}

__global__ __launch_bounds__(1024) void scan_bsums(int* __restrict__ bsum, int nb) {
    __shared__ int s[1024];
    int v = (threadIdx.x < nb) ? bsum[threadIdx.x] : 0;
    s[threadIdx.x] = v;
    __syncthreads();
    for (int off = 1; off < 1024; off <<= 1) {
        int t = (threadIdx.x >= off) ? s[threadIdx.x - off] : 0;
        __syncthreads();
        s[threadIdx.x] += t;
        __syncthreads();
    }
    if (threadIdx.x < nb) bsum[threadIdx.x] = s[threadIdx.x] - v;  // exclusive
}

__global__ __launch_bounds__(256) void scan_apply(const int* __restrict__ cnt,
                                                  const int* __restrict__ bsum,
                                                  int* __restrict__ start, int n) {
    __shared__ int s[256];
    int i = blockIdx.x * 1024 + threadIdx.x * 4;
    int4 v = make_int4(0, 0, 0, 0);
    if (i + 3 < n) {
        v = *(const int4*)(cnt + i);
    } else {
        if (i + 0 < n) v.x = cnt[i + 0];
        if (i + 1 < n) v.y = cnt[i + 1];
        if (i + 2 < n) v.z = cnt[i + 2];
        if (i + 3 < n) v.w = cnt[i + 3];
    }
    int tsum = v.x + v.y + v.z + v.w;
    s[threadIdx.x] = tsum;
    __syncthreads();
    for (int off = 1; off < 256; off <<= 1) {
        int t = (threadIdx.x >= off) ? s[threadIdx.x - off] : 0;
        __syncthreads();
        s[threadIdx.x] += t;
        __syncthreads();
    }
    int r0 = s[threadIdx.x] - tsum + bsum[blockIdx.x];
    int r1 = r0 + v.x, r2 = r1 + v.y, r3 = r2 + v.z;
    if (i + 3 < n) {
        *(int4*)(start + i) = make_int4(r0, r1, r2, r3);
    } else {
        int rr[4] = {r0, r1, r2, r3};
        for (int j = 0; j < 4 && i + j < n; j++) start[i + j] = rr[j];
    }
}

// ---- binned CSR fill: bucket = 128 consecutive dsts; append packed (dst7,src) ----
__global__ __launch_bounds__(256) void bin_edges(const int* __restrict__ ei,
                                                 const int* __restrict__ start,
                                                 int* __restrict__ bnext,
                                                 uint* __restrict__ bbuf,
                                                 int ne, int nn) {
    int e = blockIdx.x * 256 + threadIdx.x;
    if (e >= ne) return;
    int dst = ei[e];
    int src = ei[ne + e];
    if ((unsigned)dst >= (unsigned)nn || (unsigned)src >= (unsigned)nn) return;
    int b = dst >> 7;
    int base = start[b << 7];                 // bucket region base (hot, L2)
    int slot = atomicAdd(&bnext[b], 1);       // sequential append head per bucket
    bbuf[base + slot] = ((uint)(dst & 127) << 17) | (uint)src;
}

// one block per bucket: LDS counting-rank, write src to exact CSR slot (clustered 8KB)
__global__ __launch_bounds__(256) void sort_bucket(const uint* __restrict__ bbuf,
                                                   const int* __restrict__ start,
                                                   const int* __restrict__ cnt,
                                                   int* __restrict__ csr, int n) {
    __shared__ int lnext[128];
    __shared__ int sstart[128];
    const int b = blockIdx.x;
    const int d0 = b << 7;
    const int dlim = min(n, d0 + 128);        // exclusive
    if (threadIdx.x < 128) {
        lnext[threadIdx.x] = 0;
        sstart[threadIdx.x] = (d0 + threadIdx.x < n) ? start[d0 + threadIdx.x] : 0;
    }
    __syncthreads();
    const int base = sstart[0];
    const int last = dlim - 1 - d0;
    const int end = sstart[last] + cnt[d0 + last];
    for (int i = base + threadIdx.x; i < end; i += 256) {
        uint p = bbuf[i];
        int d7 = (int)(p >> 17);
        int src = (int)(p & 0x1FFFFu);
        int r = atomicAdd(&lnext[d7], 1);
        csr[sstart[d7] + r] = src;
    }
}

// legacy direct fill (fallback path only)
__global__ __launch_bounds__(256) void fill_csr(const int* __restrict__ ei,
                                                int* __restrict__ next,
                                                int* __restrict__ csr, int ne, int nn) {
    int e = blockIdx.x * 256 + threadIdx.x;
    if (e >= ne) return;
    int dst = ei[e];
    int src = ei[ne + e];
    if ((unsigned)dst >= (unsigned)nn || (unsigned)src >= (unsigned)nn) return;
    int slot = atomicAdd(&next[dst], 1);
    csr[slot] = src;
}
__global__ __launch_bounds__(256) void copy_ints(const int* __restrict__ a,
                                                 int* __restrict__ b, int n) {
    int i = blockIdx.x * 256 + threadIdx.x;
    if (i < n) b[i] = a[i];
}

// ---------------- gather (bf16 src, fp32 self): one wave per node ----------------
__global__ __launch_bounds__(256) void gather_b16(const int* __restrict__ csr,
                                                  const int* __restrict__ start,
                                                  const int* __restrict__ cnt,
                                                  const uint* __restrict__ x2b,
                                                  const float* __restrict__ x2f,
                                                  float* __restrict__ out, int nn) {
    int wave = (int)((blockIdx.x * 256 + threadIdx.x) >> 6);
    int lane = threadIdx.x & 63;
    if (wave >= nn) return;
    const int s0 = start[wave];
    const int dg = cnt[wave];
    float a0 = 0, a1 = 0, b0 = 0, b1 = 0, c0 = 0, c1 = 0, d0 = 0, d1 = 0;
    int e = 0;
    for (; e + 4 <= dg; e += 4) {
        int s1 = csr[s0 + e], s2 = csr[s0 + e + 1];
        int s3 = csr[s0 + e + 2], s4 = csr[s0 + e + 3];
        uint u1 = x2b[(size_t)s1 * 64 + lane];
        uint u2 = x2b[(size_t)s2 * 64 + lane];
        uint u3 = x2b[(size_t)s3 * 64 + lane];
        uint u4 = x2b[(size_t)s4 * 64 + lane];
        a0 += b2f_lo(u1); a1 += b2f_hi(u1);
        b0 += b2f_lo(u2); b1 += b2f_hi(u2);
        c0 += b2f_lo(u3); c1 += b2f_hi(u3);
        d0 += b2f_lo(u4); d1 += b2f_hi(u4);
    }
    for (; e < dg; e++) {
        int s1 = csr[s0 + e];
        uint u1 = x2b[(size_t)s1 * 64 + lane];
        a0 += b2f_lo(u1); a1 += b2f_hi(u1);
    }
    float2 self = ((const float2*)(x2f + (size_t)wave * 128))[lane];
    float d = (float)dg;
    float2 o;
    o.x = (a0 + b0) + (c0 + d0) - d * self.x;
    o.y = (a1 + b1) + (c1 + d1) - d * self.y;
    ((float2*)out)[(size_t)wave * 64 + lane] = o;
}

// fp32 fallback gather
__global__ __launch_bounds__(256) void gather_out(const int* __restrict__ csr,
                                                  const int* __restrict__ start,
                                                  const int* __restrict__ cnt,
                                                  const float* __restrict__ x2,
                                                  float* __restrict__ out, int nn) {
    int wave = (int)((blockIdx.x * 256 + threadIdx.x) >> 6);
    int lane = threadIdx.x & 63;
    if (wave >= nn) return;
    const int s0 = start[wave];
    const int dg = cnt[wave];
    const float2* __restrict__ base = (const float2*)x2;
    float2 acc0 = make_float2(0.f, 0.f), acc1 = make_float2(0.f, 0.f);
    int e = 0;
    for (; e + 2 <= dg; e += 2) {
        int s1 = csr[s0 + e], s2 = csr[s0 + e + 1];
        float2 v1 = base[(size_t)s1 * 64 + lane];
        float2 v2 = base[(size_t)s2 * 64 + lane];
        acc0.x += v1.x; acc0.y += v1.y;
        acc1.x += v2.x; acc1.y += v2.y;
    }
    if (e < dg) {
        int s1 = csr[s0 + e];
        float2 v1 = base[(size_t)s1 * 64 + lane];
        acc0.x += v1.x; acc0.y += v1.y;
    }
    float2 self = base[(size_t)wave * 64 + lane];
    float d = (float)dg;
    float2 o;
    o.x = acc0.x + acc1.x - d * self.x;
    o.y = acc0.y + acc1.y - d * self.y;
    ((float2*)out)[(size_t)wave * 64 + lane] = o;
}

extern "C" void kernel_launch(void* const* d_in, const int* in_sizes, int n_in,
                              void* d_out, int out_size, void* d_ws, size_t ws_size,
                              hipStream_t stream) {
    const float* x = (const float*)d_in[0];
    const int* ei = (const int*)d_in[1];
    const float* W = (const float*)d_in[2];
    // d_in[3] (bias) provably unused: cancels in out = A@x2 - x2*deg.
    float* out = (float*)d_out;

    const int n = in_sizes[0] / C_DIM;     // 100000
    const int ne = in_sizes[1] / 2;        // 1600000
    const int nb = (n + 1023) / 1024;      // scan tiles (<=1024)
    const int nbk = (n + 127) / 128;       // buckets of 128 dsts (782)

    const size_t sz_x2f = (size_t)n * C_DIM * sizeof(float);
    const size_t sz_x2b = (size_t)n * C_DIM * sizeof(ushort);
    const size_t sz_int = (size_t)n * sizeof(int);
    const size_t sz_bs = (size_t)((nb + 3) & ~3) * sizeof(int);
    const size_t sz_bn = (size_t)((nbk + 3) & ~3) * sizeof(int);
    const size_t sz_e = (size_t)ne * sizeof(int);
    const size_t need_bin = sz_x2f + sz_x2b + 2 * sz_int + sz_bs + sz_bn + 2 * sz_e;
    const size_t need_b16 = sz_x2f + sz_x2b + 3 * sz_int + sz_bs + sz_e;
    const bool use_bin = ws_size >= need_bin;
    const bool use_b16 = use_bin || ws_size >= need_b16;

    char* ws = (char*)d_ws;
    float* x2f = (float*)ws;                ws += sz_x2f;
    ushort* x2b = nullptr;
    if (use_b16) { x2b = (ushort*)ws;       ws += sz_x2b; }
    int* cnt = (int*)ws;                    ws += sz_int;
    int* start = (int*)ws;                  ws += sz_int;
    int* bsum = (int*)ws;                   ws += sz_bs;
    int *bnext = nullptr, *csr = nullptr, *next = nullptr;
    uint* bbuf = nullptr;
    if (use_bin) {
        bnext = (int*)ws;                   ws += sz_bn;
        csr = (int*)ws;                     ws += sz_e;
        bbuf = (uint*)ws;
    } else {
        next = (int*)ws;                    ws += sz_int;
        csr = (int*)ws;
    }

    zero_ints<<<(n + 255) / 256, 256, 0, stream>>>(cnt, n);
    if (use_bin) zero_ints<<<(nbk + 255) / 256, 256, 0, stream>>>(bnext, nbk);

    int ntiles = (n + 127) / 128;
    gemm_mfma<<<ntiles, 256, 0, stream>>>(x, W, x2f, x2b, n);

    int eblocks = (ne + 255) / 256;
    count_deg<<<eblocks, 256, 0, stream>>>(ei, cnt, ne, n);

    scan_partials<<<nb, 256, 0, stream>>>(cnt, bsum, n);
    scan_bsums<<<1, 1024, 0, stream>>>(bsum, nb);
    scan_apply<<<nb, 256, 0, stream>>>(cnt, bsum, start, n);

    if (use_bin) {
        bin_edges<<<eblocks, 256, 0, stream>>>(ei, start, bnext, bbuf, ne, n);
        sort_bucket<<<nbk, 256, 0, stream>>>(bbuf, start, cnt, csr, n);
    } else {
        copy_ints<<<(n + 255) / 256, 256, 0, stream>>>(start, next, n);
        fill_csr<<<eblocks, 256, 0, stream>>>(ei, next, csr, ne, n);
    }

    int gblocks = (n + 3) / 4;   // 4 waves per block, 1 node per wave
    if (use_b16)
        gather_b16<<<gblocks, 256, 0, stream>>>(csr, start, cnt, (const uint*)x2b, x2f, out, n);
    else
        gather_out<<<gblocks, 256, 0, stream>>>(csr, start, cnt, x2f, out, n);
}

// Round 10
// 337.284 us; speedup vs baseline: 1.9963x; 1.9963x over previous
//
#include <hip/hip_runtime.h>

// out[n] = sum_{e: dst_e = n} (x2[src_e] - x2[dst_e]),  x2 = x @ W   (bias cancels)
// Pipeline: MFMA bf16 GEMM x@W -> x2f (fp32) + x2b (bf16); CSR build via
// count / scan / block-aggregated binned fill / per-bucket LDS counting sort;
// gather: one wave per node; src-sum from bf16 x2, self term from fp32 x2.

#define C_DIM 128
#define EPB 8192          // edges per bin_edges2 block
#define MAXBK 1024        // max buckets supported by LDS hist (bucket = 128 dsts)

typedef __attribute__((ext_vector_type(8))) short bf16x8;
typedef __attribute__((ext_vector_type(4))) float f32x4;

__device__ __forceinline__ ushort f2b(float f) {   // fp32 -> bf16 RNE
    uint u = __float_as_uint(f);
    u = (u + 0x7FFFu + ((u >> 16) & 1u)) >> 16;
    return (ushort)u;
}
__device__ __forceinline__ float b2f_lo(uint u) { return __uint_as_float(u << 16); }
__device__ __forceinline__ float b2f_hi(uint u) { return __uint_as_float(u & 0xFFFF0000u); }

// ---------------- MFMA GEMM (unchanged) ----------------
__global__ __launch_bounds__(256) void gemm_mfma(const float* __restrict__ x,
                                                 const float* __restrict__ W,
                                                 float* __restrict__ x2f,
                                                 ushort* __restrict__ x2b,
                                                 int nrows) {
    __shared__ ushort Wt[128 * 128];   // 32 KB
    const int tid = threadIdx.x;
    for (int i = tid; i < 4096; i += 256) {
        int k = i >> 5, n0 = (i & 31) * 4;
        float4 w = *(const float4*)(W + k * 128 + n0);
        float wv[4] = {w.x, w.y, w.z, w.w};
#pragma unroll
        for (int j = 0; j < 4; j++) {
            int n = n0 + j;
            Wt[(n * 128 + k) ^ ((n & 7) << 3)] = f2b(wv[j]);
        }
    }
    __syncthreads();

    const int wv_ = tid >> 6;
    const int lane = tid & 63;
    const int ln = lane & 15, kg = lane >> 4;
    const int row_base = blockIdx.x * 128 + wv_ * 32;

    f32x4 acc[2][8];
#pragma unroll
    for (int a = 0; a < 2; a++)
#pragma unroll
        for (int b = 0; b < 8; b++) acc[a][b] = (f32x4)(0.f);

#pragma unroll
    for (int step = 0; step < 4; step++) {
        const int k0 = step * 32 + kg * 8;
        bf16x8 bfr[8];
#pragma unroll
        for (int cf = 0; cf < 8; cf++) {
            int n = cf * 16 + ln;
            bfr[cf] = *(const bf16x8*)&Wt[(n * 128 + k0) ^ ((n & 7) << 3)];
        }
#pragma unroll
        for (int mf = 0; mf < 2; mf++) {
            int row = row_base + mf * 16 + ln;
            bf16x8 afr;
#pragma unroll
            for (int j = 0; j < 8; j++) afr[j] = 0;
            if (row < nrows) {
                const float4* ap = (const float4*)(x + (size_t)row * 128 + k0);
                float4 a0 = ap[0], a1 = ap[1];
                float av[8] = {a0.x, a0.y, a0.z, a0.w, a1.x, a1.y, a1.z, a1.w};
#pragma unroll
                for (int j = 0; j < 8; j++) afr[j] = (short)f2b(av[j]);
            }
#pragma unroll
            for (int cf = 0; cf < 8; cf++)
                acc[mf][cf] = __builtin_amdgcn_mfma_f32_16x16x32_bf16(afr, bfr[cf], acc[mf][cf], 0, 0, 0);
        }
    }

#pragma unroll
    for (int mf = 0; mf < 2; mf++) {
#pragma unroll
        for (int j = 0; j < 4; j++) {
            int row = row_base + mf * 16 + kg * 4 + j;
            if (row >= nrows) continue;
#pragma unroll
            for (int cf = 0; cf < 8; cf++) {
                float v = acc[mf][cf][j];
                int col = cf * 16 + ln;
                x2f[(size_t)row * 128 + col] = v;
                if (x2b) x2b[(size_t)row * 128 + col] = f2b(v);
            }
        }
    }
}

// ---------------- CSR build ----------------
__global__ __launch_bounds__(256) void zero_ints(int* p, int n) {
    int i = blockIdx.x * 256 + threadIdx.x;
    if (i < n) p[i] = 0;
}

__global__ __launch_bounds__(256) void count_deg(const int* __restrict__ ei,
                                                 int* __restrict__ cnt, int ne, int nn) {
    int e = blockIdx.x * 256 + threadIdx.x;
    if (e >= ne) return;
    int dst = ei[e];
    if ((unsigned)dst < (unsigned)nn) atomicAdd(&cnt[dst], 1);
}

__global__ __launch_bounds__(256) void scan_partials(const int* __restrict__ cnt,
                                                     int* __restrict__ bsum, int n) {
    __shared__ int red[256];
    int i = blockIdx.x * 1024 + threadIdx.x * 4;
    int s = 0;
    if (i + 3 < n) {
        int4 v = *(const int4*)(cnt + i);
        s = v.x + v.y + v.z + v.w;
    } else {
        for (int j = i; j < n && j < i + 4; j++) s += cnt[j];
    }
    red[threadIdx.x] = s;
    __syncthreads();
    for (int off = 128; off > 0; off >>= 1) {
        if (threadIdx.x < off) red[threadIdx.x] += red[threadIdx.x + off];
        __syncthreads();
    }
    if (threadIdx.x == 0) bsum[blockIdx.x] = red[0];
}

__global__ __launch_bounds__(1024) void scan_bsums(int* __restrict__ bsum, int nb) {
    __shared__ int s[1024];
    int v = (threadIdx.x < nb) ? bsum[threadIdx.x] : 0;
    s[threadIdx.x] = v;
    __syncthreads();
    for (int off = 1; off < 1024; off <<= 1) {
        int t = (threadIdx.x >= off) ? s[threadIdx.x - off] : 0;
        __syncthreads();
        s[threadIdx.x] += t;
        __syncthreads();
    }
    if (threadIdx.x < nb) bsum[threadIdx.x] = s[threadIdx.x] - v;  // exclusive
}

__global__ __launch_bounds__(256) void scan_apply(const int* __restrict__ cnt,
                                                  const int* __restrict__ bsum,
                                                  int* __restrict__ start, int n) {
    __shared__ int s[256];
    int i = blockIdx.x * 1024 + threadIdx.x * 4;
    int4 v = make_int4(0, 0, 0, 0);
    if (i + 3 < n) {
        v = *(const int4*)(cnt + i);
    } else {
        if (i + 0 < n) v.x = cnt[i + 0];
        if (i + 1 < n) v.y = cnt[i + 1];
        if (i + 2 < n) v.z = cnt[i + 2];
        if (i + 3 < n) v.w = cnt[i + 3];
    }
    int tsum = v.x + v.y + v.z + v.w;
    s[threadIdx.x] = tsum;
    __syncthreads();
    for (int off = 1; off < 256; off <<= 1) {
        int t = (threadIdx.x >= off) ? s[threadIdx.x - off] : 0;
        __syncthreads();
        s[threadIdx.x] += t;
        __syncthreads();
    }
    int r0 = s[threadIdx.x] - tsum + bsum[blockIdx.x];
    int r1 = r0 + v.x, r2 = r1 + v.y, r3 = r2 + v.z;
    if (i + 3 < n) {
        *(int4*)(start + i) = make_int4(r0, r1, r2, r3);
    } else {
        int rr[4] = {r0, r1, r2, r3};
        for (int j = 0; j < 4 && i + j < n; j++) start[i + j] = rr[j];
    }
}

// ---- block-aggregated binned fill: one global atomic per (block, bucket) ----
// bucket = dst>>7. Per block: LDS-hist 8192 edges, reserve per-bucket ranges with a
// single atomicAdd each, then rank-and-scatter packed (dst&127)<<17|src into bbuf.
__global__ __launch_bounds__(256) void bin_edges2(const int* __restrict__ ei,
                                                  const int* __restrict__ start,
                                                  int* __restrict__ bnext,
                                                  uint* __restrict__ bbuf,
                                                  int ne, int nn, int nbk) {
    __shared__ int hist[MAXBK];
    __shared__ int base[MAXBK];
    const int e0 = blockIdx.x * EPB;
    const int e1 = min(ne, e0 + EPB);
    for (int i = threadIdx.x; i < nbk; i += 256) hist[i] = 0;
    __syncthreads();
    // pass 1: per-block bucket histogram
    for (int e = e0 + threadIdx.x; e < e1; e += 256) {
        int dst = ei[e];
        if ((unsigned)dst < (unsigned)nn) atomicAdd(&hist[dst >> 7], 1);
    }
    __syncthreads();
    // reserve global ranges: ONE atomic per nonempty bucket; fold in CSR bucket base
    for (int i = threadIdx.x; i < nbk; i += 256) {
        int h = hist[i];
        int b0 = (h > 0) ? atomicAdd(&bnext[i], h) : 0;
        base[i] = start[i << 7] + b0;
        hist[i] = 0;   // reuse as local rank counter
    }
    __syncthreads();
    // pass 2: scatter (dst re-read is L2-warm)
    for (int e = e0 + threadIdx.x; e < e1; e += 256) {
        int dst = ei[e];
        int src = ei[ne + e];
        if ((unsigned)dst >= (unsigned)nn || (unsigned)src >= (unsigned)nn) continue;
        int b = dst >> 7;
        int r = atomicAdd(&hist[b], 1);
        bbuf[base[b] + r] = ((uint)(dst & 127) << 17) | (uint)src;
    }
}

// one block per bucket: LDS counting-rank, write src to exact CSR slot (clustered ~8KB)
__global__ __launch_bounds__(256) void sort_bucket(const uint* __restrict__ bbuf,
                                                   const int* __restrict__ start,
                                                   const int* __restrict__ cnt,
                                                   int* __restrict__ csr, int n) {
    __shared__ int lnext[128];
    __shared__ int sstart[128];
    const int b = blockIdx.x;
    const int d0 = b << 7;
    const int dlim = min(n, d0 + 128);        // exclusive
    if (threadIdx.x < 128) {
        lnext[threadIdx.x] = 0;
        sstart[threadIdx.x] = (d0 + threadIdx.x < n) ? start[d0 + threadIdx.x] : 0;
    }
    __syncthreads();
    const int base = sstart[0];
    const int last = dlim - 1 - d0;
    const int end = sstart[last] + cnt[d0 + last];
    for (int i = base + threadIdx.x; i < end; i += 256) {
        uint p = bbuf[i];
        int d7 = (int)(p >> 17);
        int src = (int)(p & 0x1FFFFu);
        int r = atomicAdd(&lnext[d7], 1);
        csr[sstart[d7] + r] = src;
    }
}

// legacy direct fill (fallback path only)
__global__ __launch_bounds__(256) void fill_csr(const int* __restrict__ ei,
                                                int* __restrict__ next,
                                                int* __restrict__ csr, int ne, int nn) {
    int e = blockIdx.x * 256 + threadIdx.x;
    if (e >= ne) return;
    int dst = ei[e];
    int src = ei[ne + e];
    if ((unsigned)dst >= (unsigned)nn || (unsigned)src >= (unsigned)nn) return;
    int slot = atomicAdd(&next[dst], 1);
    csr[slot] = src;
}
__global__ __launch_bounds__(256) void copy_ints(const int* __restrict__ a,
                                                 int* __restrict__ b, int n) {
    int i = blockIdx.x * 256 + threadIdx.x;
    if (i < n) b[i] = a[i];
}

// ---------------- gather (bf16 src, fp32 self): one wave per node ----------------
__global__ __launch_bounds__(256) void gather_b16(const int* __restrict__ csr,
                                                  const int* __restrict__ start,
                                                  const int* __restrict__ cnt,
                                                  const uint* __restrict__ x2b,
                                                  const float* __restrict__ x2f,
                                                  float* __restrict__ out, int nn) {
    int wave = (int)((blockIdx.x * 256 + threadIdx.x) >> 6);
    int lane = threadIdx.x & 63;
    if (wave >= nn) return;
    const int s0 = start[wave];
    const int dg = cnt[wave];
    float a0 = 0, a1 = 0, b0 = 0, b1 = 0, c0 = 0, c1 = 0, d0 = 0, d1 = 0;
    int e = 0;
    for (; e + 4 <= dg; e += 4) {
        int s1 = csr[s0 + e], s2 = csr[s0 + e + 1];
        int s3 = csr[s0 + e + 2], s4 = csr[s0 + e + 3];
        uint u1 = x2b[(size_t)s1 * 64 + lane];
        uint u2 = x2b[(size_t)s2 * 64 + lane];
        uint u3 = x2b[(size_t)s3 * 64 + lane];
        uint u4 = x2b[(size_t)s4 * 64 + lane];
        a0 += b2f_lo(u1); a1 += b2f_hi(u1);
        b0 += b2f_lo(u2); b1 += b2f_hi(u2);
        c0 += b2f_lo(u3); c1 += b2f_hi(u3);
        d0 += b2f_lo(u4); d1 += b2f_hi(u4);
    }
    for (; e < dg; e++) {
        int s1 = csr[s0 + e];
        uint u1 = x2b[(size_t)s1 * 64 + lane];
        a0 += b2f_lo(u1); a1 += b2f_hi(u1);
    }
    float2 self = ((const float2*)(x2f + (size_t)wave * 128))[lane];
    float d = (float)dg;
    float2 o;
    o.x = (a0 + b0) + (c0 + d0) - d * self.x;
    o.y = (a1 + b1) + (c1 + d1) - d * self.y;
    ((float2*)out)[(size_t)wave * 64 + lane] = o;
}

// fp32 fallback gather
__global__ __launch_bounds__(256) void gather_out(const int* __restrict__ csr,
                                                  const int* __restrict__ start,
                                                  const int* __restrict__ cnt,
                                                  const float* __restrict__ x2,
                                                  float* __restrict__ out, int nn) {
    int wave = (int)((blockIdx.x * 256 + threadIdx.x) >> 6);
    int lane = threadIdx.x & 63;
    if (wave >= nn) return;
    const int s0 = start[wave];
    const int dg = cnt[wave];
    const float2* __restrict__ base = (const float2*)x2;
    float2 acc0 = make_float2(0.f, 0.f), acc1 = make_float2(0.f, 0.f);
    int e = 0;
    for (; e + 2 <= dg; e += 2) {
        int s1 = csr[s0 + e], s2 = csr[s0 + e + 1];
        float2 v1 = base[(size_t)s1 * 64 + lane];
        float2 v2 = base[(size_t)s2 * 64 + lane];
        acc0.x += v1.x; acc0.y += v1.y;
        acc1.x += v2.x; acc1.y += v2.y;
    }
    if (e < dg) {
        int s1 = csr[s0 + e];
        float2 v1 = base[(size_t)s1 * 64 + lane];
        acc0.x += v1.x; acc0.y += v1.y;
    }
    float2 self = base[(size_t)wave * 64 + lane];
    float d = (float)dg;
    float2 o;
    o.x = acc0.x + acc1.x - d * self.x;
    o.y = acc0.y + acc1.y - d * self.y;
    ((float2*)out)[(size_t)wave * 64 + lane] = o;
}

extern "C" void kernel_launch(void* const* d_in, const int* in_sizes, int n_in,
                              void* d_out, int out_size, void* d_ws, size_t ws_size,
                              hipStream_t stream) {
    const float* x = (const float*)d_in[0];
    const int* ei = (const int*)d_in[1];
    const float* W = (const float*)d_in[2];
    // d_in[3] (bias) provably unused: cancels in out = A@x2 - x2*deg.
    float* out = (float*)d_out;

    const int n = in_sizes[0] / C_DIM;     // 100000
    const int ne = in_sizes[1] / 2;        // 1600000
    const int nb = (n + 1023) / 1024;      // scan tiles (<=1024)
    const int nbk = (n + 127) / 128;       // buckets of 128 dsts (782)

    const size_t sz_x2f = (size_t)n * C_DIM * sizeof(float);
    const size_t sz_x2b = (size_t)n * C_DIM * sizeof(ushort);
    const size_t sz_int = (size_t)n * sizeof(int);
    const size_t sz_bs = (size_t)((nb + 3) & ~3) * sizeof(int);
    const size_t sz_bn = (size_t)((nbk + 3) & ~3) * sizeof(int);
    const size_t sz_e = (size_t)ne * sizeof(int);
    const size_t need_bin = sz_x2f + sz_x2b + 2 * sz_int + sz_bs + sz_bn + 2 * sz_e;
    const size_t need_b16 = sz_x2f + sz_x2b + 3 * sz_int + sz_bs + sz_e;
    const bool use_bin = ws_size >= need_bin && nbk <= MAXBK && n < (1 << 17);
    const bool use_b16 = use_bin || ws_size >= need_b16;

    char* ws = (char*)d_ws;
    float* x2f = (float*)ws;                ws += sz_x2f;
    ushort* x2b = nullptr;
    if (use_b16) { x2b = (ushort*)ws;       ws += sz_x2b; }
    int* cnt = (int*)ws;                    ws += sz_int;
    int* start = (int*)ws;                  ws += sz_int;
    int* bsum = (int*)ws;                   ws += sz_bs;
    int *bnext = nullptr, *csr = nullptr, *next = nullptr;
    uint* bbuf = nullptr;
    if (use_bin) {
        bnext = (int*)ws;                   ws += sz_bn;
        csr = (int*)ws;                     ws += sz_e;
        bbuf = (uint*)ws;
    } else {
        next = (int*)ws;                    ws += sz_int;
        csr = (int*)ws;
    }

    zero_ints<<<(n + 255) / 256, 256, 0, stream>>>(cnt, n);
    if (use_bin) zero_ints<<<(nbk + 255) / 256, 256, 0, stream>>>(bnext, nbk);

    int ntiles = (n + 127) / 128;
    gemm_mfma<<<ntiles, 256, 0, stream>>>(x, W, x2f, x2b, n);

    int eblocks = (ne + 255) / 256;
    count_deg<<<eblocks, 256, 0, stream>>>(ei, cnt, ne, n);

    scan_partials<<<nb, 256, 0, stream>>>(cnt, bsum, n);
    scan_bsums<<<1, 1024, 0, stream>>>(bsum, nb);
    scan_apply<<<nb, 256, 0, stream>>>(cnt, bsum, start, n);

    if (use_bin) {
        int binblocks = (ne + EPB - 1) / EPB;   // 196
        bin_edges2<<<binblocks, 256, 0, stream>>>(ei, start, bnext, bbuf, ne, n, nbk);
        sort_bucket<<<nbk, 256, 0, stream>>>(bbuf, start, cnt, csr, n);
    } else {
        copy_ints<<<(n + 255) / 256, 256, 0, stream>>>(start, next, n);
        fill_csr<<<eblocks, 256, 0, stream>>>(ei, next, csr, ne, n);
    }

    int gblocks = (n + 3) / 4;   // 4 waves per block, 1 node per wave
    if (use_b16)
        gather_b16<<<gblocks, 256, 0, stream>>>(csr, start, cnt, (const uint*)x2b, x2f, out, n);
    else
        gather_out<<<gblocks, 256, 0, stream>>>(csr, start, cnt, x2f, out, n);
}

// Round 12
// 280.446 us; speedup vs baseline: 2.4008x; 1.2027x over previous
//
#include <hip/hip_runtime.h>

// out[n] = sum_{e: dst_e = n} (x2[src_e] - x2[dst_e]),  x2 = x @ W   (bias cancels)
// Pipeline: MFMA bf16 GEMM x@W -> x2f (fp32) + x2b (bf16);
// CSR build: bucket_hist (782 buckets) / bucket_scan / block-aggregated bin fill /
// per-bucket LDS sort (which also emits per-dst start/cnt);
// gather: one wave per node; src-sum from bf16 x2, self term from fp32 x2.

#define C_DIM 128
#define EPB 8192          // edges per binning block
#define MAXBK 1024        // max buckets supported by LDS hist (bucket = 128 dsts)

typedef __attribute__((ext_vector_type(8))) short bf16x8;
typedef __attribute__((ext_vector_type(4))) float f32x4;

__device__ __forceinline__ ushort f2b(float f) {   // fp32 -> bf16 RNE
    uint u = __float_as_uint(f);
    u = (u + 0x7FFFu + ((u >> 16) & 1u)) >> 16;
    return (ushort)u;
}
__device__ __forceinline__ float b2f_lo(uint u) { return __uint_as_float(u << 16); }
__device__ __forceinline__ float b2f_hi(uint u) { return __uint_as_float(u & 0xFFFF0000u); }

// ---------------- MFMA GEMM (unchanged) ----------------
__global__ __launch_bounds__(256) void gemm_mfma(const float* __restrict__ x,
                                                 const float* __restrict__ W,
                                                 float* __restrict__ x2f,
                                                 ushort* __restrict__ x2b,
                                                 int nrows) {
    __shared__ ushort Wt[128 * 128];   // 32 KB
    const int tid = threadIdx.x;
    for (int i = tid; i < 4096; i += 256) {
        int k = i >> 5, n0 = (i & 31) * 4;
        float4 w = *(const float4*)(W + k * 128 + n0);
        float wv[4] = {w.x, w.y, w.z, w.w};
#pragma unroll
        for (int j = 0; j < 4; j++) {
            int n = n0 + j;
            Wt[(n * 128 + k) ^ ((n & 7) << 3)] = f2b(wv[j]);
        }
    }
    __syncthreads();

    const int wv_ = tid >> 6;
    const int lane = tid & 63;
    const int ln = lane & 15, kg = lane >> 4;
    const int row_base = blockIdx.x * 128 + wv_ * 32;

    f32x4 acc[2][8];
#pragma unroll
    for (int a = 0; a < 2; a++)
#pragma unroll
        for (int b = 0; b < 8; b++) acc[a][b] = (f32x4)(0.f);

#pragma unroll
    for (int step = 0; step < 4; step++) {
        const int k0 = step * 32 + kg * 8;
        bf16x8 bfr[8];
#pragma unroll
        for (int cf = 0; cf < 8; cf++) {
            int n = cf * 16 + ln;
            bfr[cf] = *(const bf16x8*)&Wt[(n * 128 + k0) ^ ((n & 7) << 3)];
        }
#pragma unroll
        for (int mf = 0; mf < 2; mf++) {
            int row = row_base + mf * 16 + ln;
            bf16x8 afr;
#pragma unroll
            for (int j = 0; j < 8; j++) afr[j] = 0;
            if (row < nrows) {
                const float4* ap = (const float4*)(x + (size_t)row * 128 + k0);
                float4 a0 = ap[0], a1 = ap[1];
                float av[8] = {a0.x, a0.y, a0.z, a0.w, a1.x, a1.y, a1.z, a1.w};
#pragma unroll
                for (int j = 0; j < 8; j++) afr[j] = (short)f2b(av[j]);
            }
#pragma unroll
            for (int cf = 0; cf < 8; cf++)
                acc[mf][cf] = __builtin_amdgcn_mfma_f32_16x16x32_bf16(afr, bfr[cf], acc[mf][cf], 0, 0, 0);
        }
    }

#pragma unroll
    for (int mf = 0; mf < 2; mf++) {
#pragma unroll
        for (int j = 0; j < 4; j++) {
            int row = row_base + mf * 16 + kg * 4 + j;
            if (row >= nrows) continue;
#pragma unroll
            for (int cf = 0; cf < 8; cf++) {
                float v = acc[mf][cf][j];
                int col = cf * 16 + ln;
                x2f[(size_t)row * 128 + col] = v;
                if (x2b) x2b[(size_t)row * 128 + col] = f2b(v);
            }
        }
    }
}

// ---------------- helpers ----------------
__global__ __launch_bounds__(256) void zero_ints(int* p, int n) {
    int i = blockIdx.x * 256 + threadIdx.x;
    if (i < n) p[i] = 0;
}

// ---------------- bucket-level CSR build (no per-dst count/scan kernels) ----------------
// Pass 1: block-aggregated histogram of bucket = dst>>7 into bcnt[nbk].
__global__ __launch_bounds__(256) void bucket_hist(const int* __restrict__ ei,
                                                   int* __restrict__ bcnt,
                                                   int ne, int nn, int nbk) {
    __shared__ int hist[MAXBK];
    const int e0 = blockIdx.x * EPB;
    const int e1 = min(ne, e0 + EPB);
    for (int i = threadIdx.x; i < nbk; i += 256) hist[i] = 0;
    __syncthreads();
    for (int e = e0 + threadIdx.x; e < e1; e += 256) {
        int dst = ei[e];
        if ((unsigned)dst < (unsigned)nn) atomicAdd(&hist[dst >> 7], 1);
    }
    __syncthreads();
    for (int i = threadIdx.x; i < nbk; i += 256) {
        int h = hist[i];
        if (h > 0) atomicAdd(&bcnt[i], h);
    }
}

// Pass 2: single-block exclusive scan bcnt[nbk] -> bstart[nbk+1]; zero bnext.
__global__ __launch_bounds__(1024) void bucket_scan(const int* __restrict__ bcnt,
                                                    int* __restrict__ bstart,
                                                    int* __restrict__ bnext, int nbk) {
    __shared__ int s[1024];
    int v = (threadIdx.x < nbk) ? bcnt[threadIdx.x] : 0;
    s[threadIdx.x] = v;
    __syncthreads();
    for (int off = 1; off < 1024; off <<= 1) {
        int t = (threadIdx.x >= off) ? s[threadIdx.x - off] : 0;
        __syncthreads();
        s[threadIdx.x] += t;
        __syncthreads();
    }
    if (threadIdx.x < nbk) {
        bstart[threadIdx.x] = s[threadIdx.x] - v;   // exclusive
        bnext[threadIdx.x] = 0;
        if (threadIdx.x == nbk - 1) bstart[nbk] = s[threadIdx.x];
    }
}

// Pass 3: block-aggregated binned fill (one global atomic per (block, bucket)).
__global__ __launch_bounds__(256) void bin_edges2(const int* __restrict__ ei,
                                                  const int* __restrict__ bstart,
                                                  int* __restrict__ bnext,
                                                  uint* __restrict__ bbuf,
                                                  int ne, int nn, int nbk) {
    __shared__ int hist[MAXBK];
    __shared__ int base[MAXBK];
    const int e0 = blockIdx.x * EPB;
    const int e1 = min(ne, e0 + EPB);
    for (int i = threadIdx.x; i < nbk; i += 256) hist[i] = 0;
    __syncthreads();
    for (int e = e0 + threadIdx.x; e < e1; e += 256) {
        int dst = ei[e];
        if ((unsigned)dst < (unsigned)nn) atomicAdd(&hist[dst >> 7], 1);
    }
    __syncthreads();
    for (int i = threadIdx.x; i < nbk; i += 256) {
        int h = hist[i];
        int b0 = (h > 0) ? atomicAdd(&bnext[i], h) : 0;
        base[i] = bstart[i] + b0;
        hist[i] = 0;   // reuse as local rank counter
    }
    __syncthreads();
    for (int e = e0 + threadIdx.x; e < e1; e += 256) {
        int dst = ei[e];
        int src = ei[ne + e];
        if ((unsigned)dst >= (unsigned)nn || (unsigned)src >= (unsigned)nn) continue;
        int b = dst >> 7;
        int r = atomicAdd(&hist[b], 1);
        bbuf[base[b] + r] = ((uint)(dst & 127) << 17) | (uint)src;
    }
}

// Pass 4: one block per bucket — LDS hist over 128 dsts, LDS scan, emit per-dst
// start/cnt to global, then counting-rank scatter src into exact CSR slots.
__global__ __launch_bounds__(256) void sort_bucket2(const uint* __restrict__ bbuf,
                                                    const int* __restrict__ bstart,
                                                    int* __restrict__ csr,
                                                    int* __restrict__ start,
                                                    int* __restrict__ cnt, int n) {
    __shared__ int h[128];    // hist, then rank counter
    __shared__ int sb[128];   // scan buffer -> per-dst global base
    const int b = blockIdx.x;
    const int d0 = b << 7;
    const int base = bstart[b];
    const int end = bstart[b + 1];
    if (threadIdx.x < 128) h[threadIdx.x] = 0;
    __syncthreads();
    for (int i = base + threadIdx.x; i < end; i += 256)
        atomicAdd(&h[bbuf[i] >> 17], 1);
    __syncthreads();
    if (threadIdx.x < 128) sb[threadIdx.x] = h[threadIdx.x];
    __syncthreads();
    for (int off = 1; off < 128; off <<= 1) {
        int t = 0;
        if (threadIdx.x < 128 && threadIdx.x >= off) t = sb[threadIdx.x - off];
        __syncthreads();
        if (threadIdx.x < 128) sb[threadIdx.x] += t;
        __syncthreads();
    }
    if (threadIdx.x < 128) {
        int excl = sb[threadIdx.x] - h[threadIdx.x];   // exclusive scan value
        int gbase = base + excl;
        sb[threadIdx.x] = gbase;
        int d = d0 + threadIdx.x;
        if (d < n) { start[d] = gbase; cnt[d] = h[threadIdx.x]; }
        h[threadIdx.x] = 0;   // reuse as rank
    }
    __syncthreads();
    for (int i = base + threadIdx.x; i < end; i += 256) {
        uint p = bbuf[i];
        int d7 = (int)(p >> 17);
        int src = (int)(p & 0x1FFFFu);
        int r = atomicAdd(&h[d7], 1);
        csr[sb[d7] + r] = src;
    }
}

// ---------------- fallback path kernels (ws too small / too many buckets) ----------------
__global__ __launch_bounds__(256) void count_deg(const int* __restrict__ ei,
                                                 int* __restrict__ cnt, int ne, int nn) {
    int e = blockIdx.x * 256 + threadIdx.x;
    if (e >= ne) return;
    int dst = ei[e];
    if ((unsigned)dst < (unsigned)nn) atomicAdd(&cnt[dst], 1);
}

__global__ __launch_bounds__(256) void scan_partials(const int* __restrict__ cnt,
                                                     int* __restrict__ bsum, int n) {
    __shared__ int red[256];
    int i = blockIdx.x * 1024 + threadIdx.x * 4;
    int s = 0;
    if (i + 3 < n) {
        int4 v = *(const int4*)(cnt + i);
        s = v.x + v.y + v.z + v.w;
    } else {
        for (int j = i; j < n && j < i + 4; j++) s += cnt[j];
    }
    red[threadIdx.x] = s;
    __syncthreads();
    for (int off = 128; off > 0; off >>= 1) {
        if (threadIdx.x < off) red[threadIdx.x] += red[threadIdx.x + off];
        __syncthreads();
    }
    if (threadIdx.x == 0) bsum[blockIdx.x] = red[0];
}

__global__ __launch_bounds__(1024) void scan_bsums(int* __restrict__ bsum, int nb) {
    __shared__ int s[1024];
    int v = (threadIdx.x < nb) ? bsum[threadIdx.x] : 0;
    s[threadIdx.x] = v;
    __syncthreads();
    for (int off = 1; off < 1024; off <<= 1) {
        int t = (threadIdx.x >= off) ? s[threadIdx.x - off] : 0;
        __syncthreads();
        s[threadIdx.x] += t;
        __syncthreads();
    }
    if (threadIdx.x < nb) bsum[threadIdx.x] = s[threadIdx.x] - v;  // exclusive
}

__global__ __launch_bounds__(256) void scan_apply(const int* __restrict__ cnt,
                                                  const int* __restrict__ bsum,
                                                  int* __restrict__ start,
                                                  int* __restrict__ next, int n) {
    __shared__ int s[256];
    int i = blockIdx.x * 1024 + threadIdx.x * 4;
    int4 v = make_int4(0, 0, 0, 0);
    if (i + 3 < n) {
        v = *(const int4*)(cnt + i);
    } else {
        if (i + 0 < n) v.x = cnt[i + 0];
        if (i + 1 < n) v.y = cnt[i + 1];
        if (i + 2 < n) v.z = cnt[i + 2];
        if (i + 3 < n) v.w = cnt[i + 3];
    }
    int tsum = v.x + v.y + v.z + v.w;
    s[threadIdx.x] = tsum;
    __syncthreads();
    for (int off = 1; off < 256; off <<= 1) {
        int t = (threadIdx.x >= off) ? s[threadIdx.x - off] : 0;
        __syncthreads();
        s[threadIdx.x] += t;
        __syncthreads();
    }
    int r0 = s[threadIdx.x] - tsum + bsum[blockIdx.x];
    int r1 = r0 + v.x, r2 = r1 + v.y, r3 = r2 + v.z;
    if (i + 3 < n) {
        *(int4*)(start + i) = make_int4(r0, r1, r2, r3);
        *(int4*)(next + i) = make_int4(r0, r1, r2, r3);
    } else {
        int rr[4] = {r0, r1, r2, r3};
        for (int j = 0; j < 4 && i + j < n; j++) {
            start[i + j] = rr[j];
            next[i + j] = rr[j];
        }
    }
}

__global__ __launch_bounds__(256) void fill_csr(const int* __restrict__ ei,
                                                int* __restrict__ next,
                                                int* __restrict__ csr, int ne, int nn) {
    int e = blockIdx.x * 256 + threadIdx.x;
    if (e >= ne) return;
    int dst = ei[e];
    int src = ei[ne + e];
    if ((unsigned)dst >= (unsigned)nn || (unsigned)src >= (unsigned)nn) return;
    int slot = atomicAdd(&next[dst], 1);
    csr[slot] = src;
}

// ---------------- gather (bf16 src, fp32 self): one wave per node ----------------
__global__ __launch_bounds__(256) void gather_b16(const int* __restrict__ csr,
                                                  const int* __restrict__ start,
                                                  const int* __restrict__ cnt,
                                                  const uint* __restrict__ x2b,
                                                  const float* __restrict__ x2f,
                                                  float* __restrict__ out, int nn) {
    int wave = (int)((blockIdx.x * 256 + threadIdx.x) >> 6);
    int lane = threadIdx.x & 63;
    if (wave >= nn) return;
    const int s0 = start[wave];
    const int dg = cnt[wave];
    float a0 = 0, a1 = 0, b0 = 0, b1 = 0, c0 = 0, c1 = 0, d0 = 0, d1 = 0;
    int e = 0;
    for (; e + 4 <= dg; e += 4) {
        int s1 = csr[s0 + e], s2 = csr[s0 + e + 1];
        int s3 = csr[s0 + e + 2], s4 = csr[s0 + e + 3];
        uint u1 = x2b[(size_t)s1 * 64 + lane];
        uint u2 = x2b[(size_t)s2 * 64 + lane];
        uint u3 = x2b[(size_t)s3 * 64 + lane];
        uint u4 = x2b[(size_t)s4 * 64 + lane];
        a0 += b2f_lo(u1); a1 += b2f_hi(u1);
        b0 += b2f_lo(u2); b1 += b2f_hi(u2);
        c0 += b2f_lo(u3); c1 += b2f_hi(u3);
        d0 += b2f_lo(u4); d1 += b2f_hi(u4);
    }
    for (; e < dg; e++) {
        int s1 = csr[s0 + e];
        uint u1 = x2b[(size_t)s1 * 64 + lane];
        a0 += b2f_lo(u1); a1 += b2f_hi(u1);
    }
    float2 self = ((const float2*)(x2f + (size_t)wave * 128))[lane];
    float d = (float)dg;
    float2 o;
    o.x = (a0 + b0) + (c0 + d0) - d * self.x;
    o.y = (a1 + b1) + (c1 + d1) - d * self.y;
    ((float2*)out)[(size_t)wave * 64 + lane] = o;
}

// fp32 fallback gather
__global__ __launch_bounds__(256) void gather_out(const int* __restrict__ csr,
                                                  const int* __restrict__ start,
                                                  const int* __restrict__ cnt,
                                                  const float* __restrict__ x2,
                                                  float* __restrict__ out, int nn) {
    int wave = (int)((blockIdx.x * 256 + threadIdx.x) >> 6);
    int lane = threadIdx.x & 63;
    if (wave >= nn) return;
    const int s0 = start[wave];
    const int dg = cnt[wave];
    const float2* __restrict__ base = (const float2*)x2;
    float2 acc0 = make_float2(0.f, 0.f), acc1 = make_float2(0.f, 0.f);
    int e = 0;
    for (; e + 2 <= dg; e += 2) {
        int s1 = csr[s0 + e], s2 = csr[s0 + e + 1];
        float2 v1 = base[(size_t)s1 * 64 + lane];
        float2 v2 = base[(size_t)s2 * 64 + lane];
        acc0.x += v1.x; acc0.y += v1.y;
        acc1.x += v2.x; acc1.y += v2.y;
    }
    if (e < dg) {
        int s1 = csr[s0 + e];
        float2 v1 = base[(size_t)s1 * 64 + lane];
        acc0.x += v1.x; acc0.y += v1.y;
    }
    float2 self = base[(size_t)wave * 64 + lane];
    float d = (float)dg;
    float2 o;
    o.x = acc0.x + acc1.x - d * self.x;
    o.y = acc0.y + acc1.y - d * self.y;
    ((float2*)out)[(size_t)wave * 64 + lane] = o;
}

extern "C" void kernel_launch(void* const* d_in, const int* in_sizes, int n_in,
                              void* d_out, int out_size, void* d_ws, size_t ws_size,
                              hipStream_t stream) {
    const float* x = (const float*)d_in[0];
    const int* ei = (const int*)d_in[1];
    const float* W = (const float*)d_in[2];
    // d_in[3] (bias) provably unused: cancels in out = A@x2 - x2*deg.
    float* out = (float*)d_out;

    const int n = in_sizes[0] / C_DIM;     // 100000
    const int ne = in_sizes[1] / 2;        // 1600000
    const int nbk = (n + 127) / 128;       // buckets of 128 dsts (782)
    const int nb = (n + 1023) / 1024;      // fallback scan tiles

    const size_t sz_x2f = (size_t)n * C_DIM * sizeof(float);
    const size_t sz_x2b = (size_t)n * C_DIM * sizeof(ushort);
    const size_t sz_int = (size_t)n * sizeof(int);
    const size_t sz_bkt = (size_t)((nbk + 4) & ~3) * sizeof(int);  // nbk(+1) ints padded
    const size_t sz_e = (size_t)ne * sizeof(int);
    const size_t sz_bs = (size_t)((nb + 3) & ~3) * sizeof(int);
    const size_t need_bin = sz_x2f + sz_x2b + 2 * sz_int + 3 * sz_bkt + 2 * sz_e;
    const size_t need_b16 = sz_x2f + sz_x2b + 3 * sz_int + sz_bs + sz_e;
    const bool use_bin = ws_size >= need_bin && nbk <= MAXBK && n < (1 << 17);
    const bool use_b16 = use_bin || ws_size >= need_b16;

    char* ws = (char*)d_ws;
    float* x2f = (float*)ws;                ws += sz_x2f;
    ushort* x2b = nullptr;
    if (use_b16) { x2b = (ushort*)ws;       ws += sz_x2b; }
    int* cnt = (int*)ws;                    ws += sz_int;
    int* start = (int*)ws;                  ws += sz_int;
    int *csr = nullptr, *next = nullptr, *bsum = nullptr;
    int *bcnt = nullptr, *bstart = nullptr, *bnext = nullptr;
    uint* bbuf = nullptr;

    if (use_bin) {
        bcnt = (int*)ws;                    ws += sz_bkt;
        bstart = (int*)ws;                  ws += sz_bkt;   // nbk+1 entries
        bnext = (int*)ws;                   ws += sz_bkt;
        csr = (int*)ws;                     ws += sz_e;
        bbuf = (uint*)ws;
    } else {
        bsum = (int*)ws;                    ws += sz_bs;
        next = (int*)ws;                    ws += sz_int;
        csr = (int*)ws;
    }

    int ntiles = (n + 127) / 128;
    int binblocks = (ne + EPB - 1) / EPB;   // 196
    int eblocks = (ne + 255) / 256;

    if (use_bin) {
        zero_ints<<<(nbk + 255) / 256, 256, 0, stream>>>(bcnt, nbk);

        gemm_mfma<<<ntiles, 256, 0, stream>>>(x, W, x2f, x2b, n);

        bucket_hist<<<binblocks, 256, 0, stream>>>(ei, bcnt, ne, n, nbk);
        bucket_scan<<<1, 1024, 0, stream>>>(bcnt, bstart, bnext, nbk);
        bin_edges2<<<binblocks, 256, 0, stream>>>(ei, bstart, bnext, bbuf, ne, n, nbk);
        sort_bucket2<<<nbk, 256, 0, stream>>>(bbuf, bstart, csr, start, cnt, n);
    } else {
        zero_ints<<<(n + 255) / 256, 256, 0, stream>>>(cnt, n);
        gemm_mfma<<<ntiles, 256, 0, stream>>>(x, W, x2f, x2b, n);
        count_deg<<<eblocks, 256, 0, stream>>>(ei, cnt, ne, n);
        scan_partials<<<nb, 256, 0, stream>>>(cnt, bsum, n);
        scan_bsums<<<1, 1024, 0, stream>>>(bsum, nb);
        scan_apply<<<nb, 256, 0, stream>>>(cnt, bsum, start, next, n);
        fill_csr<<<eblocks, 256, 0, stream>>>(ei, next, csr, ne, n);
    }

    int gblocks = (n + 3) / 4;   // 4 waves per block, 1 node per wave
    if (use_b16)
        gather_b16<<<gblocks, 256, 0, stream>>>(csr, start, cnt, (const uint*)x2b, x2f, out, n);
    else
        gather_out<<<gblocks, 256, 0, stream>>>(csr, start, cnt, x2f, out, n);
}